// Round 1
// baseline (752.078 us; speedup 1.0000x reference)
//
#include <hip/hip_runtime.h>
#include <hip/hip_bf16.h>

// Problem constants
constexpr int B_ = 2, HQ_ = 16, HP_ = 8, S_ = 2048, D_ = 64, DV_ = 128;
constexpr float LAMB0 = 0.8f;
constexpr float EPSV = 1e-5f;
constexpr float NEG_BIG = -1.0e30f;

// Tiling
constexpr int TQ = 64, TK = 32;
constexpr int QSTR = 68;   // 64 + 4 pad (16B-aligned rows, 2-way-free banks for ty strides)
constexpr int KSTR = 68;
constexpr int VSTR = 132;  // 128 + 4 pad
constexpr int PSTR = 32;   // P tile aliased into K buffer: 64x32 fits 32x68

// ---------------------------------------------------------------------------
// Flash-style dual-head differential attention.
// Grid: 512 blocks = (b, hp) x 32 q-tiles; block = 256 threads (4 waves).
// Thread grid 16(ty: 4 q-rows each) x 16(tx: 2 k-cols / 8 dv-cols each).
// ghostmax == online softmax with init m=0, l=1 (the implicit zero logit).
// ---------------------------------------------------------------------------
__launch_bounds__(256, 2)
__global__ void diffattn_fwd(const float* __restrict__ qg,
                             const float* __restrict__ kg,
                             const float* __restrict__ vg,
                             const float* __restrict__ lq1,
                             const float* __restrict__ lk1,
                             const float* __restrict__ lq2,
                             const float* __restrict__ lk2,
                             float* __restrict__ Obuf) {
  __shared__ float Qs[2][TQ][QSTR];
  __shared__ float KPs[2][TK * KSTR];  // K tile [32][68]  OR  P tile [64][32] (aliased)
  __shared__ float Vs[TK][VSTR];

  const int tid = threadIdx.x;
  const int tx = tid & 15;
  const int ty = tid >> 4;

  // Block mapping with causal load-balance pairing: qt = 0,31,1,30,...
  const int t = blockIdx.x;
  const int bh = t & 15;
  const int b = bh >> 3;
  const int hp = bh & 7;
  const int u = t >> 4;
  const int qt = (u & 1) ? (31 - (u >> 1)) : (u >> 1);
  const int q0 = qt * TQ;

  // lambda = exp(lq1.lk1) - exp(lq2.lk2) + 0.8  (uniform; cheap per block)
  float d1 = 0.f, d2 = 0.f;
  for (int i = 0; i < D_; ++i) {
    d1 += lq1[i] * lk1[i];
    d2 += lq2[i] * lk2[i];
  }
  const float lam = __expf(d1) - __expf(d2) + LAMB0;

  // Stage Q for both heads of the pair
  for (int h = 0; h < 2; ++h) {
    const float* qh = qg + (((size_t)b * HQ_ + (2 * hp + h)) * S_ + q0) * D_;
#pragma unroll
    for (int it = 0; it < 4; ++it) {
      int idx = it * 256 + tid;
      int row = idx >> 4, c4 = idx & 15;
      float4 val = *reinterpret_cast<const float4*>(qh + row * D_ + c4 * 4);
      *reinterpret_cast<float4*>(&Qs[h][row][c4 * 4]) = val;
    }
  }

  // Online-softmax state: ghostmax init m=0, l=1
  float m[2][4], l[2][4], O[2][4][8];
#pragma unroll
  for (int h = 0; h < 2; ++h)
#pragma unroll
    for (int i = 0; i < 4; ++i) {
      m[h][i] = 0.f;
      l[h][i] = 1.f;
#pragma unroll
      for (int d = 0; d < 8; ++d) O[h][i][d] = 0.f;
    }

  const int nkt = (q0 + TQ) / TK;
  for (int kt = 0; kt < nkt; ++kt) {
    const int k0 = kt * TK;
    __syncthreads();  // prev PV reads done (and Q staged, for kt=0)

    // Stage K (both heads)
    for (int h = 0; h < 2; ++h) {
      const float* kh = kg + (((size_t)b * HQ_ + (2 * hp + h)) * S_ + k0) * D_;
#pragma unroll
      for (int it = 0; it < 2; ++it) {
        int idx = it * 256 + tid;
        int row = idx >> 4, c4 = idx & 15;
        float4 val = *reinterpret_cast<const float4*>(kh + row * D_ + c4 * 4);
        *reinterpret_cast<float4*>(&KPs[h][row * KSTR + c4 * 4]) = val;
      }
    }
    // Stage V (shared by both heads)
    {
      const float* vh = vg + (((size_t)b * HP_ + hp) * S_ + k0) * DV_;
#pragma unroll
      for (int it = 0; it < 4; ++it) {
        int idx = it * 256 + tid;
        int row = idx >> 5, c4 = idx & 31;
        float4 val = *reinterpret_cast<const float4*>(vh + row * DV_ + c4 * 4);
        *reinterpret_cast<float4*>(&Vs[row][c4 * 4]) = val;
      }
    }
    __syncthreads();

    // QK^T: s[h][i][j] for q row q0+ty*4+i, k col k0+tx*2+j
    float s[2][4][2] = {};
    for (int d0 = 0; d0 < D_; d0 += 4) {
      float4 kf[2][2], qf[2][4];
#pragma unroll
      for (int h = 0; h < 2; ++h)
#pragma unroll
        for (int j = 0; j < 2; ++j)
          kf[h][j] = *reinterpret_cast<const float4*>(&KPs[h][(tx * 2 + j) * KSTR + d0]);
#pragma unroll
      for (int h = 0; h < 2; ++h)
#pragma unroll
        for (int i = 0; i < 4; ++i)
          qf[h][i] = *reinterpret_cast<const float4*>(&Qs[h][ty * 4 + i][d0]);
#pragma unroll
      for (int h = 0; h < 2; ++h)
#pragma unroll
        for (int i = 0; i < 4; ++i)
#pragma unroll
          for (int j = 0; j < 2; ++j)
            s[h][i][j] += qf[h][i].x * kf[h][j].x + qf[h][i].y * kf[h][j].y +
                          qf[h][i].z * kf[h][j].z + qf[h][i].w * kf[h][j].w;
    }

    // scale + causal mask + online softmax update
#pragma unroll
    for (int h = 0; h < 2; ++h)
#pragma unroll
      for (int i = 0; i < 4; ++i) {
        const int qgidx = q0 + ty * 4 + i;
        float s0 = s[h][i][0] * 0.125f;
        float s1 = s[h][i][1] * 0.125f;
        if (k0 + tx * 2 + 0 > qgidx) s0 = NEG_BIG;
        if (k0 + tx * 2 + 1 > qgidx) s1 = NEG_BIG;
        float rmax = fmaxf(s0, s1);
#pragma unroll
        for (int o = 1; o < 16; o <<= 1) rmax = fmaxf(rmax, __shfl_xor(rmax, o));
        const float mnew = fmaxf(m[h][i], rmax);  // m >= 0 always (ghost logit)
        const float p0 = __expf(s0 - mnew);
        const float p1 = __expf(s1 - mnew);
        float rsum = p0 + p1;
#pragma unroll
        for (int o = 1; o < 16; o <<= 1) rsum += __shfl_xor(rsum, o);
        const float f = __expf(m[h][i] - mnew);
        l[h][i] = l[h][i] * f + rsum;
        m[h][i] = mnew;
#pragma unroll
        for (int d = 0; d < 8; ++d) O[h][i][d] *= f;
        s[h][i][0] = p0;
        s[h][i][1] = p1;
      }

    __syncthreads();  // all K reads done before P overwrites the K buffer
#pragma unroll
    for (int h = 0; h < 2; ++h)
#pragma unroll
      for (int i = 0; i < 4; ++i)
        *reinterpret_cast<float2*>(&KPs[h][(ty * 4 + i) * PSTR + tx * 2]) =
            make_float2(s[h][i][0], s[h][i][1]);
    __syncthreads();  // P visible

    // PV: O[q][dv] += P[q][k] * V[k][dv]; thread covers 4q x 8dv x 2h
    const int dv0 = tx * 8;
    for (int kk = 0; kk < TK; kk += 4) {
      float4 pf[2][4];
#pragma unroll
      for (int h = 0; h < 2; ++h)
#pragma unroll
        for (int i = 0; i < 4; ++i)
          pf[h][i] = *reinterpret_cast<const float4*>(&KPs[h][(ty * 4 + i) * PSTR + kk]);
#pragma unroll
      for (int c = 0; c < 4; ++c) {
        float4 va = *reinterpret_cast<const float4*>(&Vs[kk + c][dv0]);
        float4 vb = *reinterpret_cast<const float4*>(&Vs[kk + c][dv0 + 4]);
#pragma unroll
        for (int h = 0; h < 2; ++h)
#pragma unroll
          for (int i = 0; i < 4; ++i) {
            const float pw = (c == 0) ? pf[h][i].x
                           : (c == 1) ? pf[h][i].y
                           : (c == 2) ? pf[h][i].z
                                      : pf[h][i].w;
            O[h][i][0] += pw * va.x;
            O[h][i][1] += pw * va.y;
            O[h][i][2] += pw * va.z;
            O[h][i][3] += pw * va.w;
            O[h][i][4] += pw * vb.x;
            O[h][i][5] += pw * vb.y;
            O[h][i][6] += pw * vb.z;
            O[h][i][7] += pw * vb.w;
          }
      }
    }
  }

  // Epilogue: combined = O0/l0 - lam * O1/l1 -> ws (layout [B][HP][S][DV])
  float* ob = Obuf + (((size_t)(b * HP_ + hp)) * S_ + q0) * DV_;
  const int dv0 = tx * 8;
#pragma unroll
  for (int i = 0; i < 4; ++i) {
    const int qi = ty * 4 + i;
    const float inv0 = 1.f / l[0][i];
    const float inv1 = lam / l[1][i];
    float r[8];
#pragma unroll
    for (int d = 0; d < 8; ++d) r[d] = O[0][i][d] * inv0 - O[1][i][d] * inv1;
    *reinterpret_cast<float4*>(ob + (size_t)qi * DV_ + dv0) =
        make_float4(r[0], r[1], r[2], r[3]);
    *reinterpret_cast<float4*>(ob + (size_t)qi * DV_ + dv0 + 4) =
        make_float4(r[4], r[5], r[6], r[7]);
  }
}

// ---------------------------------------------------------------------------
// GroupNorm. Key fact: torch-style reshape [B,8,S,128] -> [B,1024,2048]
// preserves flat order, so each of the 32 (b,group) stat regions is a
// CONTIGUOUS 131072-float chunk of Obuf. weight/bias channel c = hp*128+s/16.
// ---------------------------------------------------------------------------
__global__ void gn_stats(const float* __restrict__ O, float* __restrict__ stats) {
  const int g = blockIdx.x >> 3;       // 32 groups
  const int slice = blockIdx.x & 7;    // 8 blocks per group
  const size_t base = (size_t)g * 131072 + (size_t)slice * 16384;
  const int tid = threadIdx.x;
  float sum = 0.f, ss = 0.f;
#pragma unroll 4
  for (int it = 0; it < 16; ++it) {
    int idx = it * 256 + tid;
    float4 x = *reinterpret_cast<const float4*>(O + base + (size_t)idx * 4);
    sum += x.x + x.y + x.z + x.w;
    ss += x.x * x.x + x.y * x.y + x.z * x.z + x.w * x.w;
  }
#pragma unroll
  for (int o = 1; o < 64; o <<= 1) {
    sum += __shfl_xor(sum, o);
    ss += __shfl_xor(ss, o);
  }
  __shared__ float red[8];
  if ((tid & 63) == 0) {
    red[(tid >> 6) * 2] = sum;
    red[(tid >> 6) * 2 + 1] = ss;
  }
  __syncthreads();
  if (tid == 0) {
    atomicAdd(&stats[2 * g + 0], red[0] + red[2] + red[4] + red[6]);
    atomicAdd(&stats[2 * g + 1], red[1] + red[3] + red[5] + red[7]);
  }
}

__global__ void gn_apply(const float* __restrict__ O, const float* __restrict__ stats,
                         const float* __restrict__ gw, const float* __restrict__ gb,
                         float* __restrict__ out) {
  const size_t f = ((size_t)blockIdx.x * 256 + threadIdx.x) * 4;
  const int g = (int)(f >> 17);
  const int sidx = (int)((f >> 7) & 2047);
  const int hp = (int)((f >> 18) & 7);
  const int c = hp * 128 + (sidx >> 4);
  const float mean = stats[2 * g + 0] * (1.f / 131072.f);
  const float var = stats[2 * g + 1] * (1.f / 131072.f) - mean * mean;
  const float sc = rsqrtf(var + EPSV) * gw[c] * 0.2f;  // fold (1-lambda_init)
  const float bi = gb[c] * 0.2f;
  float4 x = *reinterpret_cast<const float4*>(O + f);
  float4 y;
  y.x = (x.x - mean) * sc + bi;
  y.y = (x.y - mean) * sc + bi;
  y.z = (x.z - mean) * sc + bi;
  y.w = (x.w - mean) * sc + bi;
  *reinterpret_cast<float4*>(out + f) = y;
}

extern "C" void kernel_launch(void* const* d_in, const int* in_sizes, int n_in,
                              void* d_out, int out_size, void* d_ws, size_t ws_size,
                              hipStream_t stream) {
  const float* q = (const float*)d_in[0];
  const float* k = (const float*)d_in[1];
  const float* v = (const float*)d_in[2];
  const float* lq1 = (const float*)d_in[3];
  const float* lk1 = (const float*)d_in[4];
  const float* lq2 = (const float*)d_in[5];
  const float* lk2 = (const float*)d_in[6];
  const float* gw = (const float*)d_in[7];
  const float* gb = (const float*)d_in[8];
  float* out = (float*)d_out;

  float* Obuf = (float*)d_ws;  // [B][HP][S][DV] fp32 = 16 MiB
  float* stats = (float*)((char*)d_ws + (size_t)B_ * HP_ * S_ * DV_ * sizeof(float));

  hipMemsetAsync(stats, 0, 32 * 2 * sizeof(float), stream);  // ws is re-poisoned 0xAA
  diffattn_fwd<<<dim3(512), dim3(256), 0, stream>>>(q, k, v, lq1, lk1, lq2, lk2, Obuf);
  gn_stats<<<dim3(256), dim3(256), 0, stream>>>(Obuf, stats);
  gn_apply<<<dim3(4096), dim3(256), 0, stream>>>(Obuf, stats, gw, gb, out);
}

// Round 2
// 320.994 us; speedup vs baseline: 2.3430x; 2.3430x over previous
//
#include <hip/hip_runtime.h>
#include <hip/hip_bf16.h>

constexpr int B_ = 2, HQ_ = 16, HP_ = 8, S_ = 2048, D_ = 64, DV_ = 128;
constexpr float LAMB0 = 0.8f;
constexpr float EPSV = 1e-5f;

constexpr int TQ = 64, TK = 32;
constexpr int KSTR = 72;  // shorts per K-tile row (64+8 pad) = 144 B, 16B-aligned
constexpr int VSTR = 40;  // shorts per V^T row (32+8 pad) = 80 B, 16B-aligned

typedef __attribute__((ext_vector_type(8))) short bf16x8;
typedef __attribute__((ext_vector_type(4))) float f32x4;
typedef __attribute__((ext_vector_type(4))) short short4v;

__device__ __forceinline__ unsigned short f2bf(float x) {
  unsigned u = __float_as_uint(x);
  u += 0x7FFFu + ((u >> 16) & 1u);          // RNE
  return (unsigned short)(u >> 16);
}
__device__ __forceinline__ float bf2f(unsigned short h) {
  return __uint_as_float((unsigned)h << 16);
}
__device__ __forceinline__ unsigned pack2(unsigned short a, unsigned short b) {
  return (unsigned)a | ((unsigned)b << 16);
}

// ---------------------------------------------------------------------------
// Differential flash attention, bf16x3 MFMA emulation (fp32-grade accuracy).
// Grid 512 = (b,hp)x32 q-tiles (causal-paired). Block 256 = 4 waves x 16 q.
// S^T = K*Q^T via mfma(A=K, B=Q): lane holds P[q=li][k=4g+r] -> PV A-frag
// built with 8 shfl + 4 cndmask (no LDS round trip).
// ---------------------------------------------------------------------------
__launch_bounds__(256, 2)
__global__ void diffattn_fwd(const float* __restrict__ qg, const float* __restrict__ kg,
                             const float* __restrict__ vg,
                             const float* __restrict__ lq1, const float* __restrict__ lk1,
                             const float* __restrict__ lq2, const float* __restrict__ lk2,
                             float* __restrict__ Obuf) {
  __shared__ short Kl[2][2][TK][KSTR];   // [head][hi/lo][k][d] 18.4 KB
  __shared__ short Vt[2][DV_][VSTR];     // [hi/lo][dv][k]      20.5 KB

  const int tid = threadIdx.x;
  const int w = tid >> 6;       // wave: 16-q strip
  const int l = tid & 63;
  const int g = l >> 4;
  const int li = l & 15;

  const int t = blockIdx.x;
  const int bh = t & 15;
  const int b = bh >> 3;
  const int hp = bh & 7;
  const int u = t >> 4;
  const int qt = (u & 1) ? (31 - (u >> 1)) : (u >> 1);
  const int q0 = qt * TQ;
  const int qw = q0 + w * 16;

  float d1 = 0.f, d2 = 0.f;
  for (int i = 0; i < D_; ++i) { d1 += lq1[i] * lk1[i]; d2 += lq2[i] * lk2[i]; }
  const float lam = __expf(d1) - __expf(d2) + LAMB0;

  // ---- Q fragments in registers, hi/lo split: B-operand of S^T ----
  bf16x8 qhi[2][2], qlo[2][2];   // [head][d-chunk]
#pragma unroll
  for (int h = 0; h < 2; ++h)
#pragma unroll
    for (int c = 0; c < 2; ++c) {
      const float* p = qg + (((size_t)b * HQ_ + 2 * hp + h) * S_ + qw + li) * D_ + c * 32 + g * 8;
      float4 a = *reinterpret_cast<const float4*>(p);
      float4 bq = *reinterpret_cast<const float4*>(p + 4);
      float xs[8] = {a.x, a.y, a.z, a.w, bq.x, bq.y, bq.z, bq.w};
      union { bf16x8 v; unsigned us[4]; } H, L;
#pragma unroll
      for (int j = 0; j < 4; ++j) {
        unsigned short h0 = f2bf(xs[2 * j]), h1 = f2bf(xs[2 * j + 1]);
        H.us[j] = pack2(h0, h1);
        L.us[j] = pack2(f2bf(xs[2 * j] - bf2f(h0)), f2bf(xs[2 * j + 1] - bf2f(h1)));
      }
      qhi[h][c] = H.v;
      qlo[h][c] = L.v;
    }

  float mreg[2] = {0.f, 0.f};     // ghostmax: m init 0
  float lreg[2] = {1.f, 1.f};     // implicit zero logit
  const f32x4 zero4 = {0.f, 0.f, 0.f, 0.f};
  f32x4 Oacc[2][8];
#pragma unroll
  for (int h = 0; h < 2; ++h)
#pragma unroll
    for (int d = 0; d < 8; ++d) Oacc[h][d] = zero4;

  // staging assignments
  const int khs = tid >> 7;          // K: head
  const int ktf = tid & 127;
  const float* kb0 = kg + ((size_t)b * HQ_ + 2 * hp + khs) * S_ * D_;
  const int vdv = tid & 127;         // V: dv lane
  const int vkq0 = tid >> 7;
  const float* vb0 = vg + ((size_t)b * HP_ + hp) * S_ * DV_ + vdv;

  const int nkt = (q0 + TQ) / TK;
  for (int kt = 0; kt < nkt; ++kt) {
    const int k0 = kt * TK;
    __syncthreads();   // previous tile's LDS reads complete

    { // stage K (both heads, hi+lo)
      const float* kb = kb0 + (size_t)k0 * D_;
#pragma unroll
      for (int it = 0; it < 4; ++it) {
        int f = ktf + 128 * it;
        int row = f >> 4, c4 = (f & 15) * 4;
        float4 x = *reinterpret_cast<const float4*>(kb + row * D_ + c4);
        unsigned short h0 = f2bf(x.x), h1 = f2bf(x.y), h2 = f2bf(x.z), h3 = f2bf(x.w);
        short4v hi = {(short)h0, (short)h1, (short)h2, (short)h3};
        short4v lo = {(short)f2bf(x.x - bf2f(h0)), (short)f2bf(x.y - bf2f(h1)),
                      (short)f2bf(x.z - bf2f(h2)), (short)f2bf(x.w - bf2f(h3))};
        *reinterpret_cast<short4v*>(&Kl[khs][0][row][c4]) = hi;
        *reinterpret_cast<short4v*>(&Kl[khs][1][row][c4]) = lo;
      }
    }
    { // stage V^T (hi+lo): strided-coalesced reads, b64 transposed writes
      const float* vb = vb0 + (size_t)k0 * DV_;
#pragma unroll
      for (int it = 0; it < 4; ++it) {
        int kq = vkq0 + 2 * it;
        float x0 = vb[(size_t)(kq * 4 + 0) * DV_];
        float x1 = vb[(size_t)(kq * 4 + 1) * DV_];
        float x2 = vb[(size_t)(kq * 4 + 2) * DV_];
        float x3 = vb[(size_t)(kq * 4 + 3) * DV_];
        unsigned short h0 = f2bf(x0), h1 = f2bf(x1), h2 = f2bf(x2), h3 = f2bf(x3);
        short4v hi = {(short)h0, (short)h1, (short)h2, (short)h3};
        short4v lo = {(short)f2bf(x0 - bf2f(h0)), (short)f2bf(x1 - bf2f(h1)),
                      (short)f2bf(x2 - bf2f(h2)), (short)f2bf(x3 - bf2f(h3))};
        *reinterpret_cast<short4v*>(&Vt[0][vdv][kq * 4]) = hi;
        *reinterpret_cast<short4v*>(&Vt[1][vdv][kq * 4]) = lo;
      }
    }
    __syncthreads();   // staged tile visible

    if (k0 > qw + 15) continue;   // fully-masked for this wave (barriers stay matched)
    const bool needmask = (k0 + TK - 1 > qw);

    bf16x8 Ahi[2], Alo[2];

#pragma unroll
    for (int h = 0; h < 2; ++h) {
      // K fragments (A-operand of S^T)
      bf16x8 kf[2][2][2];  // [hl][msub][chunk]
#pragma unroll
      for (int hl = 0; hl < 2; ++hl)
#pragma unroll
        for (int ms = 0; ms < 2; ++ms)
#pragma unroll
          for (int c = 0; c < 2; ++c)
            kf[hl][ms][c] =
                *reinterpret_cast<const bf16x8*>(&Kl[h][hl][ms * 16 + li][c * 32 + g * 8]);

      f32x4 sT[2] = {zero4, zero4};
      __builtin_amdgcn_s_setprio(1);
#pragma unroll
      for (int ms = 0; ms < 2; ++ms)
#pragma unroll
        for (int c = 0; c < 2; ++c) {
          sT[ms] = __builtin_amdgcn_mfma_f32_16x16x32_bf16(kf[0][ms][c], qhi[h][c], sT[ms], 0, 0, 0);
          sT[ms] = __builtin_amdgcn_mfma_f32_16x16x32_bf16(kf[0][ms][c], qlo[h][c], sT[ms], 0, 0, 0);
          sT[ms] = __builtin_amdgcn_mfma_f32_16x16x32_bf16(kf[1][ms][c], qhi[h][c], sT[ms], 0, 0, 0);
        }
      __builtin_amdgcn_s_setprio(0);

      // ---- online ghostmax for q = qw + li (lane holds k = 16ms + 4g + r) ----
      const int qglob = qw + li;
      float sv[2][4];
#pragma unroll
      for (int ms = 0; ms < 2; ++ms)
#pragma unroll
        for (int r = 0; r < 4; ++r) {
          float v = sT[ms][r] * 0.125f;
          if (needmask && (k0 + ms * 16 + g * 4 + r > qglob)) v = -1e30f;
          sv[ms][r] = v;
        }
      float tmax = fmaxf(fmaxf(fmaxf(sv[0][0], sv[0][1]), fmaxf(sv[0][2], sv[0][3])),
                         fmaxf(fmaxf(sv[1][0], sv[1][1]), fmaxf(sv[1][2], sv[1][3])));
      tmax = fmaxf(tmax, __shfl_xor(tmax, 16));
      tmax = fmaxf(tmax, __shfl_xor(tmax, 32));
      const float mnew = fmaxf(mreg[h], tmax);
      const float fh = __expf(mreg[h] - mnew);
      float p[2][4];
      float psum = 0.f;
#pragma unroll
      for (int ms = 0; ms < 2; ++ms)
#pragma unroll
        for (int r = 0; r < 4; ++r) {
          p[ms][r] = __expf(sv[ms][r] - mnew);
          psum += p[ms][r];
        }
      psum += __shfl_xor(psum, 16);
      psum += __shfl_xor(psum, 32);
      lreg[h] = lreg[h] * fh + psum;
      mreg[h] = mnew;
      if (!__all(fh == 1.0f)) {   // rescale O rows (factor for row 4g+r from lane 20g+r)
        float fr[4];
#pragma unroll
        for (int r = 0; r < 4; ++r) fr[r] = __shfl(fh, 20 * g + r);
#pragma unroll
        for (int d = 0; d < 8; ++d) {
          f32x4 o = Oacc[h][d];
          o[0] *= fr[0]; o[1] *= fr[1]; o[2] *= fr[2]; o[3] *= fr[3];
          Oacc[h][d] = o;
        }
      }

      // ---- P -> bf16 hi/lo, lane exchange into PV A-fragment layout ----
      unsigned ph0a = pack2(f2bf(p[0][0]), f2bf(p[0][1]));
      unsigned ph0b = pack2(f2bf(p[0][2]), f2bf(p[0][3]));
      unsigned ph1a = pack2(f2bf(p[1][0]), f2bf(p[1][1]));
      unsigned ph1b = pack2(f2bf(p[1][2]), f2bf(p[1][3]));
      float pl[2][4];
#pragma unroll
      for (int ms = 0; ms < 2; ++ms)
#pragma unroll
        for (int r = 0; r < 4; ++r) pl[ms][r] = p[ms][r] - bf2f(f2bf(p[ms][r]));
      unsigned pl0a = pack2(f2bf(pl[0][0]), f2bf(pl[0][1]));
      unsigned pl0b = pack2(f2bf(pl[0][2]), f2bf(pl[0][3]));
      unsigned pl1a = pack2(f2bf(pl[1][0]), f2bf(pl[1][1]));
      unsigned pl1b = pack2(f2bf(pl[1][2]), f2bf(pl[1][3]));

      const int srcA = 32 * (g & 1) + li;
      const int srcB = srcA + 16;
      const bool hiMs = (g >> 1) != 0;
      union { bf16x8 v; unsigned us[4]; } AH, AL;
      {
        unsigned a0 = (unsigned)__shfl((int)ph0a, srcA), b0 = (unsigned)__shfl((int)ph1a, srcA);
        unsigned a1 = (unsigned)__shfl((int)ph0b, srcA), b1 = (unsigned)__shfl((int)ph1b, srcA);
        unsigned a2 = (unsigned)__shfl((int)ph0a, srcB), b2 = (unsigned)__shfl((int)ph1a, srcB);
        unsigned a3 = (unsigned)__shfl((int)ph0b, srcB), b3 = (unsigned)__shfl((int)ph1b, srcB);
        AH.us[0] = hiMs ? b0 : a0; AH.us[1] = hiMs ? b1 : a1;
        AH.us[2] = hiMs ? b2 : a2; AH.us[3] = hiMs ? b3 : a3;
      }
      {
        unsigned a0 = (unsigned)__shfl((int)pl0a, srcA), b0 = (unsigned)__shfl((int)pl1a, srcA);
        unsigned a1 = (unsigned)__shfl((int)pl0b, srcA), b1 = (unsigned)__shfl((int)pl1b, srcA);
        unsigned a2 = (unsigned)__shfl((int)pl0a, srcB), b2 = (unsigned)__shfl((int)pl1a, srcB);
        unsigned a3 = (unsigned)__shfl((int)pl0b, srcB), b3 = (unsigned)__shfl((int)pl1b, srcB);
        AL.us[0] = hiMs ? b0 : a0; AL.us[1] = hiMs ? b1 : a1;
        AL.us[2] = hiMs ? b2 : a2; AL.us[3] = hiMs ? b3 : a3;
      }
      Ahi[h] = AH.v;
      Alo[h] = AL.v;
    }

    // ---- PV: O += P * V  (Ph*Vh + Pl*Vh + Ph*Vl) ----
    __builtin_amdgcn_s_setprio(1);
#pragma unroll
    for (int dvt = 0; dvt < 8; ++dvt) {
      bf16x8 vh = *reinterpret_cast<const bf16x8*>(&Vt[0][dvt * 16 + li][g * 8]);
      bf16x8 vl = *reinterpret_cast<const bf16x8*>(&Vt[1][dvt * 16 + li][g * 8]);
#pragma unroll
      for (int h = 0; h < 2; ++h) {
        f32x4 acc = Oacc[h][dvt];
        acc = __builtin_amdgcn_mfma_f32_16x16x32_bf16(Ahi[h], vh, acc, 0, 0, 0);
        acc = __builtin_amdgcn_mfma_f32_16x16x32_bf16(Alo[h], vh, acc, 0, 0, 0);
        acc = __builtin_amdgcn_mfma_f32_16x16x32_bf16(Ahi[h], vl, acc, 0, 0, 0);
        Oacc[h][dvt] = acc;
      }
    }
    __builtin_amdgcn_s_setprio(0);
  }

  // ---- epilogue: (O0/l0 - lam*O1/l1) -> Obuf [B][HP][S][DV] ----
  float rl0[4], rl1[4];
#pragma unroll
  for (int r = 0; r < 4; ++r) {
    rl0[r] = 1.f / __shfl(lreg[0], 20 * g + r);
    rl1[r] = lam / __shfl(lreg[1], 20 * g + r);
  }
  float* ob = Obuf + ((size_t)(b * HP_ + hp)) * S_ * DV_;
#pragma unroll
  for (int dvt = 0; dvt < 8; ++dvt)
#pragma unroll
    for (int r = 0; r < 4; ++r) {
      float vres = Oacc[0][dvt][r] * rl0[r] - Oacc[1][dvt][r] * rl1[r];
      ob[(size_t)(qw + g * 4 + r) * DV_ + dvt * 16 + li] = vres;
    }
}

// ---------------------------------------------------------------------------
// GroupNorm (unchanged from R1 — each (b,group) is a contiguous 131072-f chunk)
// ---------------------------------------------------------------------------
__global__ void gn_stats(const float* __restrict__ O, float* __restrict__ stats) {
  const int g = blockIdx.x >> 3;
  const int slice = blockIdx.x & 7;
  const size_t base = (size_t)g * 131072 + (size_t)slice * 16384;
  const int tid = threadIdx.x;
  float sum = 0.f, ss = 0.f;
#pragma unroll 4
  for (int it = 0; it < 16; ++it) {
    int idx = it * 256 + tid;
    float4 x = *reinterpret_cast<const float4*>(O + base + (size_t)idx * 4);
    sum += x.x + x.y + x.z + x.w;
    ss += x.x * x.x + x.y * x.y + x.z * x.z + x.w * x.w;
  }
#pragma unroll
  for (int o = 1; o < 64; o <<= 1) {
    sum += __shfl_xor(sum, o);
    ss += __shfl_xor(ss, o);
  }
  __shared__ float red[8];
  if ((tid & 63) == 0) {
    red[(tid >> 6) * 2] = sum;
    red[(tid >> 6) * 2 + 1] = ss;
  }
  __syncthreads();
  if (tid == 0) {
    atomicAdd(&stats[2 * g + 0], red[0] + red[2] + red[4] + red[6]);
    atomicAdd(&stats[2 * g + 1], red[1] + red[3] + red[5] + red[7]);
  }
}

__global__ void gn_apply(const float* __restrict__ O, const float* __restrict__ stats,
                         const float* __restrict__ gw, const float* __restrict__ gb,
                         float* __restrict__ out) {
  const size_t f = ((size_t)blockIdx.x * 256 + threadIdx.x) * 4;
  const int g = (int)(f >> 17);
  const int sidx = (int)((f >> 7) & 2047);
  const int hp = (int)((f >> 18) & 7);
  const int c = hp * 128 + (sidx >> 4);
  const float mean = stats[2 * g + 0] * (1.f / 131072.f);
  const float var = stats[2 * g + 1] * (1.f / 131072.f) - mean * mean;
  const float sc = rsqrtf(var + EPSV) * gw[c] * 0.2f;
  const float bi = gb[c] * 0.2f;
  float4 x = *reinterpret_cast<const float4*>(O + f);
  float4 y;
  y.x = (x.x - mean) * sc + bi;
  y.y = (x.y - mean) * sc + bi;
  y.z = (x.z - mean) * sc + bi;
  y.w = (x.w - mean) * sc + bi;
  *reinterpret_cast<float4*>(out + f) = y;
}

extern "C" void kernel_launch(void* const* d_in, const int* in_sizes, int n_in,
                              void* d_out, int out_size, void* d_ws, size_t ws_size,
                              hipStream_t stream) {
  const float* q = (const float*)d_in[0];
  const float* k = (const float*)d_in[1];
  const float* v = (const float*)d_in[2];
  const float* lq1 = (const float*)d_in[3];
  const float* lk1 = (const float*)d_in[4];
  const float* lq2 = (const float*)d_in[5];
  const float* lk2 = (const float*)d_in[6];
  const float* gw = (const float*)d_in[7];
  const float* gb = (const float*)d_in[8];
  float* out = (float*)d_out;

  float* Obuf = (float*)d_ws;  // [B][HP][S][DV] fp32 = 16 MiB
  float* stats = (float*)((char*)d_ws + (size_t)B_ * HP_ * S_ * DV_ * sizeof(float));

  hipMemsetAsync(stats, 0, 32 * 2 * sizeof(float), stream);
  diffattn_fwd<<<dim3(512), dim3(256), 0, stream>>>(q, k, v, lq1, lk1, lq2, lk2, Obuf);
  gn_stats<<<dim3(256), dim3(256), 0, stream>>>(Obuf, stats);
  gn_apply<<<dim3(4096), dim3(256), 0, stream>>>(Obuf, stats, gw, gb, out);
}

// Round 3
// 309.155 us; speedup vs baseline: 2.4327x; 1.0383x over previous
//
#include <hip/hip_runtime.h>
#include <hip/hip_bf16.h>

constexpr int B_ = 2, HQ_ = 16, HP_ = 8, S_ = 2048, D_ = 64, DV_ = 128;
constexpr float LAMB0 = 0.8f;
constexpr float EPSV = 1e-5f;

constexpr int TQ = 64, TK = 32;
constexpr int KSTR = 72;  // shorts per K-tile row (64+8 pad) = 144 B, 16B-aligned
constexpr int VSTR = 40;  // shorts per V^T row (32+8 pad) = 80 B, 16B-aligned

typedef __attribute__((ext_vector_type(8))) short bf16x8;
typedef __attribute__((ext_vector_type(4))) float f32x4;
typedef __attribute__((ext_vector_type(4))) short short4v;

__device__ __forceinline__ unsigned short f2bf(float x) {
  unsigned u = __float_as_uint(x);
  u += 0x7FFFu + ((u >> 16) & 1u);  // RNE
  return (unsigned short)(u >> 16);
}
__device__ __forceinline__ float bf2f(unsigned short h) {
  return __uint_as_float((unsigned)h << 16);
}
__device__ __forceinline__ unsigned pack2(unsigned short a, unsigned short b) {
  return (unsigned)a | ((unsigned)b << 16);
}

// ---------------------------------------------------------------------------
// Differential flash attention, bf16x3 MFMA emulation, software-pipelined:
//   iter t: [issue global loads t+1] [compute t from buf t&1]
//           [cvt+ds_write t+1 -> buf (t+1)&1] [one barrier]
// Double-buffered LDS => single barrier/iter; load latency hidden by compute.
// Heads interleaved in softmax for ILP; defer-max (THR=8) skips rescale.
// ---------------------------------------------------------------------------
__launch_bounds__(256, 2)
__global__ void diffattn_fwd(const float* __restrict__ qg, const float* __restrict__ kg,
                             const float* __restrict__ vg,
                             const float* __restrict__ lq1, const float* __restrict__ lk1,
                             const float* __restrict__ lq2, const float* __restrict__ lk2,
                             float* __restrict__ Obuf) {
  __shared__ short Kl[2][2][2][TK][KSTR];  // [buf][head][hi/lo][k][d]  36.9 KB
  __shared__ short Vt[2][2][DV_][VSTR];    // [buf][hi/lo][dv][k]       41.0 KB

  const int tid = threadIdx.x;
  const int w = tid >> 6;
  const int l = tid & 63;
  const int g = l >> 4;
  const int li = l & 15;

  const int t = blockIdx.x;
  const int bh = t & 15;
  const int b = bh >> 3;
  const int hp = bh & 7;
  const int u = t >> 4;
  const int qt = (u & 1) ? (31 - (u >> 1)) : (u >> 1);
  const int q0 = qt * TQ;
  const int qw = q0 + w * 16;

  float d1 = 0.f, d2 = 0.f;
  for (int i = 0; i < D_; ++i) { d1 += lq1[i] * lk1[i]; d2 += lq2[i] * lk2[i]; }
  const float lam = __expf(d1) - __expf(d2) + LAMB0;

  // ---- Q fragments in registers, hi/lo split ----
  bf16x8 qhi[2][2], qlo[2][2];
#pragma unroll
  for (int h = 0; h < 2; ++h)
#pragma unroll
    for (int c = 0; c < 2; ++c) {
      const float* p = qg + (((size_t)b * HQ_ + 2 * hp + h) * S_ + qw + li) * D_ + c * 32 + g * 8;
      float4 a = *reinterpret_cast<const float4*>(p);
      float4 bq = *reinterpret_cast<const float4*>(p + 4);
      float xs[8] = {a.x, a.y, a.z, a.w, bq.x, bq.y, bq.z, bq.w};
      union { bf16x8 v; unsigned us[4]; } H, L;
#pragma unroll
      for (int j = 0; j < 4; ++j) {
        unsigned short h0 = f2bf(xs[2 * j]), h1 = f2bf(xs[2 * j + 1]);
        H.us[j] = pack2(h0, h1);
        L.us[j] = pack2(f2bf(xs[2 * j] - bf2f(h0)), f2bf(xs[2 * j + 1] - bf2f(h1)));
      }
      qhi[h][c] = H.v;
      qlo[h][c] = L.v;
    }

  float mreg[2] = {0.f, 0.f};
  float lreg[2] = {1.f, 1.f};
  const f32x4 zero4 = {0.f, 0.f, 0.f, 0.f};
  f32x4 Oacc[2][8];
#pragma unroll
  for (int h = 0; h < 2; ++h)
#pragma unroll
    for (int d = 0; d < 8; ++d) Oacc[h][d] = zero4;

  // staging roles
  const int khs = tid >> 7;
  const int ktf = tid & 127;
  const float* kb0 = kg + ((size_t)b * HQ_ + 2 * hp + khs) * S_ * D_;
  const int vdv = tid & 127;
  const int vkq0 = tid >> 7;
  const float* vb0 = vg + ((size_t)b * HP_ + hp) * S_ * DV_ + vdv;

  float4 kreg[4];
  float vreg[16];

  auto issue_loads = [&](int k0) {
    const float* kb = kb0 + (size_t)k0 * D_;
#pragma unroll
    for (int it = 0; it < 4; ++it) {
      int f = ktf + 128 * it;
      kreg[it] = *reinterpret_cast<const float4*>(kb + (f >> 4) * D_ + (f & 15) * 4);
    }
    const float* vb = vb0 + (size_t)k0 * DV_;
#pragma unroll
    for (int it = 0; it < 4; ++it) {
      int kq = vkq0 + 2 * it;
#pragma unroll
      for (int c = 0; c < 4; ++c) vreg[it * 4 + c] = vb[(size_t)(kq * 4 + c) * DV_];
    }
  };

  auto cvt_write = [&](int bufp) {
#pragma unroll
    for (int it = 0; it < 4; ++it) {
      int f = ktf + 128 * it;
      int row = f >> 4, c4 = (f & 15) * 4;
      float4 x = kreg[it];
      unsigned short h0 = f2bf(x.x), h1 = f2bf(x.y), h2 = f2bf(x.z), h3 = f2bf(x.w);
      short4v hi = {(short)h0, (short)h1, (short)h2, (short)h3};
      short4v lo = {(short)f2bf(x.x - bf2f(h0)), (short)f2bf(x.y - bf2f(h1)),
                    (short)f2bf(x.z - bf2f(h2)), (short)f2bf(x.w - bf2f(h3))};
      *reinterpret_cast<short4v*>(&Kl[bufp][khs][0][row][c4]) = hi;
      *reinterpret_cast<short4v*>(&Kl[bufp][khs][1][row][c4]) = lo;
    }
#pragma unroll
    for (int it = 0; it < 4; ++it) {
      int kq = vkq0 + 2 * it;
      float x0 = vreg[it * 4 + 0], x1 = vreg[it * 4 + 1];
      float x2 = vreg[it * 4 + 2], x3 = vreg[it * 4 + 3];
      unsigned short h0 = f2bf(x0), h1 = f2bf(x1), h2 = f2bf(x2), h3 = f2bf(x3);
      short4v hi = {(short)h0, (short)h1, (short)h2, (short)h3};
      short4v lo = {(short)f2bf(x0 - bf2f(h0)), (short)f2bf(x1 - bf2f(h1)),
                    (short)f2bf(x2 - bf2f(h2)), (short)f2bf(x3 - bf2f(h3))};
      *reinterpret_cast<short4v*>(&Vt[bufp][0][vdv][kq * 4]) = hi;
      *reinterpret_cast<short4v*>(&Vt[bufp][1][vdv][kq * 4]) = lo;
    }
  };

  const int nkt = (q0 + TQ) / TK;

  // prologue: stage tile 0
  issue_loads(0);
  cvt_write(0);
  __syncthreads();

  for (int kt = 0; kt < nkt; ++kt) {
    const int k0 = kt * TK;
    const int p_ = kt & 1;

    if (kt + 1 < nkt) issue_loads((kt + 1) * TK);

    if (k0 <= qw + 15) {
      const bool needmask = (k0 + TK - 1 > qw);

      // ---- QK^T for both heads ----
      f32x4 sT[2][2];
#pragma unroll
      for (int h = 0; h < 2; ++h) {
        bf16x8 kf[2][2][2];
#pragma unroll
        for (int hl = 0; hl < 2; ++hl)
#pragma unroll
          for (int ms = 0; ms < 2; ++ms)
#pragma unroll
            for (int c = 0; c < 2; ++c)
              kf[hl][ms][c] = *reinterpret_cast<const bf16x8*>(
                  &Kl[p_][h][hl][ms * 16 + li][c * 32 + g * 8]);
        sT[h][0] = zero4;
        sT[h][1] = zero4;
        __builtin_amdgcn_s_setprio(1);
#pragma unroll
        for (int ms = 0; ms < 2; ++ms)
#pragma unroll
          for (int c = 0; c < 2; ++c) {
            sT[h][ms] = __builtin_amdgcn_mfma_f32_16x16x32_bf16(kf[0][ms][c], qhi[h][c], sT[h][ms], 0, 0, 0);
            sT[h][ms] = __builtin_amdgcn_mfma_f32_16x16x32_bf16(kf[0][ms][c], qlo[h][c], sT[h][ms], 0, 0, 0);
            sT[h][ms] = __builtin_amdgcn_mfma_f32_16x16x32_bf16(kf[1][ms][c], qhi[h][c], sT[h][ms], 0, 0, 0);
          }
        __builtin_amdgcn_s_setprio(0);
      }

      // ---- interleaved ghostmax (both heads' chains in flight) ----
      const int qglob = qw + li;
      float sv[2][2][4];
#pragma unroll
      for (int h = 0; h < 2; ++h)
#pragma unroll
        for (int ms = 0; ms < 2; ++ms)
#pragma unroll
          for (int r = 0; r < 4; ++r) {
            float v = sT[h][ms][r] * 0.125f;
            if (needmask && (k0 + ms * 16 + g * 4 + r > qglob)) v = -1e30f;
            sv[h][ms][r] = v;
          }
      float tmax[2];
#pragma unroll
      for (int h = 0; h < 2; ++h)
        tmax[h] = fmaxf(fmaxf(fmaxf(sv[h][0][0], sv[h][0][1]), fmaxf(sv[h][0][2], sv[h][0][3])),
                        fmaxf(fmaxf(sv[h][1][0], sv[h][1][1]), fmaxf(sv[h][1][2], sv[h][1][3])));
#pragma unroll
      for (int h = 0; h < 2; ++h) tmax[h] = fmaxf(tmax[h], __shfl_xor(tmax[h], 16));
#pragma unroll
      for (int h = 0; h < 2; ++h) tmax[h] = fmaxf(tmax[h], __shfl_xor(tmax[h], 32));

      // defer-max: rescale only if some row grew its max by > 8
      if (__any((tmax[0] > mreg[0] + 8.f) | (tmax[1] > mreg[1] + 8.f))) {
        float fh[2];
#pragma unroll
        for (int h = 0; h < 2; ++h) {
          const float mnew = fmaxf(mreg[h], tmax[h]);
          fh[h] = __expf(mreg[h] - mnew);
          mreg[h] = mnew;
          lreg[h] *= fh[h];
        }
#pragma unroll
        for (int h = 0; h < 2; ++h) {
          float fr[4];
#pragma unroll
          for (int r = 0; r < 4; ++r) fr[r] = __shfl(fh[h], 20 * g + r);
#pragma unroll
          for (int d = 0; d < 8; ++d) {
            f32x4 o = Oacc[h][d];
            o[0] *= fr[0]; o[1] *= fr[1]; o[2] *= fr[2]; o[3] *= fr[3];
            Oacc[h][d] = o;
          }
        }
      }

      float p[2][2][4], psum[2];
#pragma unroll
      for (int h = 0; h < 2; ++h) {
        psum[h] = 0.f;
#pragma unroll
        for (int ms = 0; ms < 2; ++ms)
#pragma unroll
          for (int r = 0; r < 4; ++r) {
            p[h][ms][r] = __expf(sv[h][ms][r] - mreg[h]);
            psum[h] += p[h][ms][r];
          }
      }
#pragma unroll
      for (int h = 0; h < 2; ++h) psum[h] += __shfl_xor(psum[h], 16);
#pragma unroll
      for (int h = 0; h < 2; ++h) psum[h] += __shfl_xor(psum[h], 32);
#pragma unroll
      for (int h = 0; h < 2; ++h) lreg[h] += psum[h];

      // ---- P -> bf16 hi/lo, lane exchange into PV A-fragments ----
      bf16x8 Ahi[2], Alo[2];
      const int srcA = 32 * (g & 1) + li;
      const int srcB = srcA + 16;
      const bool hiMs = (g >> 1) != 0;
#pragma unroll
      for (int h = 0; h < 2; ++h) {
        unsigned ph0a = pack2(f2bf(p[h][0][0]), f2bf(p[h][0][1]));
        unsigned ph0b = pack2(f2bf(p[h][0][2]), f2bf(p[h][0][3]));
        unsigned ph1a = pack2(f2bf(p[h][1][0]), f2bf(p[h][1][1]));
        unsigned ph1b = pack2(f2bf(p[h][1][2]), f2bf(p[h][1][3]));
        float pl[2][4];
#pragma unroll
        for (int ms = 0; ms < 2; ++ms)
#pragma unroll
          for (int r = 0; r < 4; ++r) pl[ms][r] = p[h][ms][r] - bf2f(f2bf(p[h][ms][r]));
        unsigned pl0a = pack2(f2bf(pl[0][0]), f2bf(pl[0][1]));
        unsigned pl0b = pack2(f2bf(pl[0][2]), f2bf(pl[0][3]));
        unsigned pl1a = pack2(f2bf(pl[1][0]), f2bf(pl[1][1]));
        unsigned pl1b = pack2(f2bf(pl[1][2]), f2bf(pl[1][3]));
        union { bf16x8 v; unsigned us[4]; } AH, AL;
        {
          unsigned a0 = (unsigned)__shfl((int)ph0a, srcA), b0 = (unsigned)__shfl((int)ph1a, srcA);
          unsigned a1 = (unsigned)__shfl((int)ph0b, srcA), b1 = (unsigned)__shfl((int)ph1b, srcA);
          unsigned a2 = (unsigned)__shfl((int)ph0a, srcB), b2 = (unsigned)__shfl((int)ph1a, srcB);
          unsigned a3 = (unsigned)__shfl((int)ph0b, srcB), b3 = (unsigned)__shfl((int)ph1b, srcB);
          AH.us[0] = hiMs ? b0 : a0; AH.us[1] = hiMs ? b1 : a1;
          AH.us[2] = hiMs ? b2 : a2; AH.us[3] = hiMs ? b3 : a3;
        }
        {
          unsigned a0 = (unsigned)__shfl((int)pl0a, srcA), b0 = (unsigned)__shfl((int)pl1a, srcA);
          unsigned a1 = (unsigned)__shfl((int)pl0b, srcA), b1 = (unsigned)__shfl((int)pl1b, srcA);
          unsigned a2 = (unsigned)__shfl((int)pl0a, srcB), b2 = (unsigned)__shfl((int)pl1a, srcB);
          unsigned a3 = (unsigned)__shfl((int)pl0b, srcB), b3 = (unsigned)__shfl((int)pl1b, srcB);
          AL.us[0] = hiMs ? b0 : a0; AL.us[1] = hiMs ? b1 : a1;
          AL.us[2] = hiMs ? b2 : a2; AL.us[3] = hiMs ? b3 : a3;
        }
        Ahi[h] = AH.v;
        Alo[h] = AL.v;
      }

      // ---- PV ----
      __builtin_amdgcn_s_setprio(1);
#pragma unroll
      for (int dvt = 0; dvt < 8; ++dvt) {
        bf16x8 vh = *reinterpret_cast<const bf16x8*>(&Vt[p_][0][dvt * 16 + li][g * 8]);
        bf16x8 vl = *reinterpret_cast<const bf16x8*>(&Vt[p_][1][dvt * 16 + li][g * 8]);
#pragma unroll
        for (int h = 0; h < 2; ++h) {
          f32x4 acc = Oacc[h][dvt];
          acc = __builtin_amdgcn_mfma_f32_16x16x32_bf16(Ahi[h], vh, acc, 0, 0, 0);
          acc = __builtin_amdgcn_mfma_f32_16x16x32_bf16(Alo[h], vh, acc, 0, 0, 0);
          acc = __builtin_amdgcn_mfma_f32_16x16x32_bf16(Ahi[h], vl, acc, 0, 0, 0);
          Oacc[h][dvt] = acc;
        }
      }
      __builtin_amdgcn_s_setprio(0);
    }

    if (kt + 1 < nkt) {
      cvt_write((kt + 1) & 1);
      __syncthreads();
    }
  }

  // ---- epilogue ----
  float rl0[4], rl1[4];
#pragma unroll
  for (int r = 0; r < 4; ++r) {
    rl0[r] = 1.f / __shfl(lreg[0], 20 * g + r);
    rl1[r] = lam / __shfl(lreg[1], 20 * g + r);
  }
  float* ob = Obuf + ((size_t)(b * HP_ + hp)) * S_ * DV_;
#pragma unroll
  for (int dvt = 0; dvt < 8; ++dvt)
#pragma unroll
    for (int r = 0; r < 4; ++r) {
      float vres = Oacc[0][dvt][r] * rl0[r] - Oacc[1][dvt][r] * rl1[r];
      ob[(size_t)(qw + g * 4 + r) * DV_ + dvt * 16 + li] = vres;
    }
}

// ---------------------------------------------------------------------------
// GroupNorm — contiguous 131072-float chunks per (b,group); 1024-block stats.
// ---------------------------------------------------------------------------
__global__ void gn_stats(const float* __restrict__ O, float* __restrict__ stats) {
  const int g = blockIdx.x >> 5;
  const int slice = blockIdx.x & 31;
  const size_t base = (size_t)g * 131072 + (size_t)slice * 4096;
  const int tid = threadIdx.x;
  float sum = 0.f, ss = 0.f;
#pragma unroll
  for (int it = 0; it < 4; ++it) {
    int idx = it * 256 + tid;
    float4 x = *reinterpret_cast<const float4*>(O + base + (size_t)idx * 4);
    sum += x.x + x.y + x.z + x.w;
    ss += x.x * x.x + x.y * x.y + x.z * x.z + x.w * x.w;
  }
#pragma unroll
  for (int o = 1; o < 64; o <<= 1) {
    sum += __shfl_xor(sum, o);
    ss += __shfl_xor(ss, o);
  }
  __shared__ float red[8];
  if ((tid & 63) == 0) {
    red[(tid >> 6) * 2] = sum;
    red[(tid >> 6) * 2 + 1] = ss;
  }
  __syncthreads();
  if (tid == 0) {
    atomicAdd(&stats[2 * g + 0], red[0] + red[2] + red[4] + red[6]);
    atomicAdd(&stats[2 * g + 1], red[1] + red[3] + red[5] + red[7]);
  }
}

__global__ void gn_apply(const float* __restrict__ O, const float* __restrict__ stats,
                         const float* __restrict__ gw, const float* __restrict__ gb,
                         float* __restrict__ out) {
  const size_t f = ((size_t)blockIdx.x * 256 + threadIdx.x) * 4;
  const int g = (int)(f >> 17);
  const int sidx = (int)((f >> 7) & 2047);
  const int hp = (int)((f >> 18) & 7);
  const int c = hp * 128 + (sidx >> 4);
  const float mean = stats[2 * g + 0] * (1.f / 131072.f);
  const float var = stats[2 * g + 1] * (1.f / 131072.f) - mean * mean;
  const float sc = rsqrtf(var + EPSV) * gw[c] * 0.2f;
  const float bi = gb[c] * 0.2f;
  float4 x = *reinterpret_cast<const float4*>(O + f);
  float4 y;
  y.x = (x.x - mean) * sc + bi;
  y.y = (x.y - mean) * sc + bi;
  y.z = (x.z - mean) * sc + bi;
  y.w = (x.w - mean) * sc + bi;
  *reinterpret_cast<float4*>(out + f) = y;
}

extern "C" void kernel_launch(void* const* d_in, const int* in_sizes, int n_in,
                              void* d_out, int out_size, void* d_ws, size_t ws_size,
                              hipStream_t stream) {
  const float* q = (const float*)d_in[0];
  const float* k = (const float*)d_in[1];
  const float* v = (const float*)d_in[2];
  const float* lq1 = (const float*)d_in[3];
  const float* lk1 = (const float*)d_in[4];
  const float* lq2 = (const float*)d_in[5];
  const float* lk2 = (const float*)d_in[6];
  const float* gw = (const float*)d_in[7];
  const float* gb = (const float*)d_in[8];
  float* out = (float*)d_out;

  float* Obuf = (float*)d_ws;  // [B][HP][S][DV] fp32 = 16 MiB
  float* stats = (float*)((char*)d_ws + (size_t)B_ * HP_ * S_ * DV_ * sizeof(float));

  hipMemsetAsync(stats, 0, 32 * 2 * sizeof(float), stream);
  diffattn_fwd<<<dim3(512), dim3(256), 0, stream>>>(q, k, v, lq1, lk1, lq2, lk2, Obuf);
  gn_stats<<<dim3(1024), dim3(256), 0, stream>>>(Obuf, stats);
  gn_apply<<<dim3(4096), dim3(256), 0, stream>>>(Obuf, stats, gw, gb, out);
}